// Round 10
// baseline (3121.048 us; speedup 1.0000x reference)
//
#include <hip/hip_runtime.h>

#define LL 256
#define BB 128
#define NLEV 48

typedef float  floatx4 __attribute__((ext_vector_type(4)));
typedef short  short8  __attribute__((ext_vector_type(8)));

struct Params {
  const float* inputs;
  const float* ioux_w[2]; const float* ioux_b[2];
  const float* iouh_w[2]; const float* iouh_b[2];
  const float* fx_w[2];   const float* fx_b[2];
  const float* fh_w[2];   const float* fh_b[2];
};

__device__ __forceinline__ unsigned short f2bf(float f) {
  unsigned u = __float_as_uint(f);
  u += 0x7fffu + ((u >> 16) & 1u);
  return (unsigned short)(u >> 16);
}
__device__ __forceinline__ float bf2f(unsigned u) { return __uint_as_float(u << 16); }
__device__ __forceinline__ float sigm(float x) { return 1.0f / (1.0f + __expf(-x)); }
__device__ __forceinline__ float tanh_(float x) { return 1.0f - 2.0f / (1.0f + __expf(2.0f * x)); }

// ---------------------------------------------------------------------------
// prep: bf16 inputs; w16x row-major gate-planar (xproj GEMM); w16h in MFMA
// B-FRAGMENT layout: value(d, cc, k) at [((d*64+nf)*8+ks)*512 + lane*8 + e],
// nf=cc>>4, lane=((k&31)>>3)*16+(cc&15), ks=k>>5, e=k&7 — one wave's
// B-fragment for (nf,ks) is a contiguous, coalesced 1KB load.
// ---------------------------------------------------------------------------
__global__ __launch_bounds__(256) void prep_kernel(Params p,
    unsigned short* a16, unsigned short* w16x, unsigned short* w16h,
    float* bias, int* lvcnt) {
  size_t tid = (size_t)blockIdx.x * blockDim.x + threadIdx.x;
  size_t nth = (size_t)gridDim.x * blockDim.x;

  const float4* in4 = (const float4*)p.inputs;
  for (size_t i = tid; i < 2097152u; i += nth) {
    float4 v = in4[i];
    ((ushort4*)a16)[i] = make_ushort4(f2bf(v.x), f2bf(v.y), f2bf(v.z), f2bf(v.w));
  }
  for (size_t i = tid; i < 524288u; i += nth) {
    int d = (int)(i >> 18); int r = (int)(i & 262143);
    int cc = r >> 8; int k = r & 255;
    float sx = (cc < 768) ? p.ioux_w[d][cc * 256 + k] : p.fx_w[d][(cc - 768) * 256 + k];
    float sh = (cc < 768) ? p.iouh_w[d][cc * 256 + k] : p.fh_w[d][(cc - 768) * 256 + k];
    w16x[i] = f2bf(sx);
    int nf = cc >> 4, lcc = cc & 15;
    int ks = k >> 5, kr = k & 31;
    int lane = (kr >> 3) * 16 + lcc, e = kr & 7;
    w16h[((size_t)(d * 64 + nf) * 8 + ks) * 512 + lane * 8 + e] = f2bf(sh);
  }
  for (size_t i = tid; i < 2048u; i += nth) {
    int d = (int)(i >> 10); int cc = (int)(i & 1023);
    bias[i] = (cc < 768) ? (p.ioux_b[d][cc] + p.iouh_b[d][cc])
                         : (p.fx_b[d][cc - 768] + p.fh_b[d][cc - 768]);
  }
  for (size_t i = tid; i < 2u * NLEV; i += nth) lvcnt[i] = 0;
}

// ---------------------------------------------------------------------------
// levels: per-b tree walks -> dt heights, td depths; children CSR.
// ---------------------------------------------------------------------------
__global__ __launch_bounds__(256) void levels_kernel(
    const int* __restrict__ parents, int* __restrict__ lev_g,
    int* __restrict__ csr_off, int* __restrict__ csr_dat, int* __restrict__ lvcnt) {
  __shared__ int parL[256], lvdt[256], lvtd[256];
  __shared__ int cmax[257], ccnt[257], coff[257], ccur[257];
  int b = blockIdx.x, t = threadIdx.x;

  parL[t] = parents[t * BB + b];
  for (int v = t; v < 257; v += 256) { cmax[v] = -1; ccnt[v] = 0; }
  __syncthreads();

  if (t == 0) {
    lvtd[0] = 0;
    for (int i = 1; i < 256; ++i) lvtd[i] = lvtd[parL[i]] + 1;
  }
  if (t == 1) {
    for (int i = 255; i >= 1; --i) {
      int l = cmax[i] + 1;
      lvdt[i] = l;
      int p = parL[i];
      if (cmax[p] < l) cmax[p] = l;
    }
    lvdt[0] = cmax[0] + 1;
  }
  __syncthreads();

  int l1 = min(lvdt[t], NLEV - 1);
  int l2 = min(lvtd[t], NLEV - 1);
  if (t >= 1) atomicAdd(&ccnt[parL[t]], 1);
  lev_g[b * 256 + t] = l1;
  lev_g[32768 + b * 256 + t] = l2;
  __syncthreads();

  if (t == 0) {
    int s = 0;
    for (int i = 0; i < 257; ++i) { coff[i] = s; s += ccnt[i]; }
  }
  __syncthreads();
  for (int v = t; v < 257; v += 256) ccur[v] = coff[v];
  __syncthreads();
  if (t >= 1) {
    int pos = atomicAdd(&ccur[parL[t]], 1);
    csr_dat[b * 256 + pos] = t;
  }
  for (int v = t; v < 257; v += 256) csr_off[b * 260 + v] = coff[v];
}

// ---------------------------------------------------------------------------
// xproj GEMM, tiled: 128x128 tile, BK=64, LDS-staged. Grid (256, 16).
// ---------------------------------------------------------------------------
__global__ __launch_bounds__(256) void xproj_gemm(
    const unsigned short* __restrict__ a16,
    const unsigned short* __restrict__ w16x,
    unsigned short* __restrict__ xp) {
  __shared__ unsigned short As[128 * 72], Bs[128 * 72];
  int t = threadIdx.x;
  int w = t >> 6, lane = t & 63, l16 = lane & 15, quad = lane >> 4;
  int m0 = blockIdx.x * 128;
  int d = blockIdx.y >> 3;
  int cc0 = (blockIdx.y & 7) * 128;
  const unsigned short* Bg = w16x + ((size_t)d * 1024 + cc0) * 256;
  int lr = t >> 3, seg = t & 7;

  floatx4 acc[4][4];
#pragma unroll
  for (int i = 0; i < 4; ++i)
#pragma unroll
    for (int j = 0; j < 4; ++j) acc[i][j] = (floatx4){0.f, 0.f, 0.f, 0.f};

  for (int ck = 0; ck < 4; ++ck) {
    int k0 = ck * 64;
#pragma unroll
    for (int it = 0; it < 4; ++it) {
      int row = it * 32 + lr;
      *(uint4*)&As[row * 72 + seg * 8] =
          *(const uint4*)(a16 + (size_t)(m0 + row) * 256 + k0 + seg * 8);
      *(uint4*)&Bs[row * 72 + seg * 8] =
          *(const uint4*)(Bg + (size_t)row * 256 + k0 + seg * 8);
    }
    __syncthreads();
#pragma unroll
    for (int kc = 0; kc < 2; ++kc) {
      int kg = kc * 4 + quad;
      short8 af[4], bf[4];
#pragma unroll
      for (int mf = 0; mf < 4; ++mf)
        af[mf] = *(const short8*)&As[((w & 1) * 64 + mf * 16 + l16) * 72 + kg * 8];
#pragma unroll
      for (int nf = 0; nf < 4; ++nf)
        bf[nf] = *(const short8*)&Bs[((w >> 1) * 64 + nf * 16 + l16) * 72 + kg * 8];
#pragma unroll
      for (int mf = 0; mf < 4; ++mf)
#pragma unroll
        for (int nf = 0; nf < 4; ++nf)
          acc[mf][nf] = __builtin_amdgcn_mfma_f32_16x16x32_bf16(af[mf], bf[nf], acc[mf][nf], 0, 0, 0);
    }
    __syncthreads();
  }
  unsigned short* out = xp + (size_t)d * 33554432u;
#pragma unroll
  for (int mf = 0; mf < 4; ++mf)
#pragma unroll
    for (int nf = 0; nf < 4; ++nf)
#pragma unroll
      for (int r = 0; r < 4; ++r) {
        int row = m0 + (w & 1) * 64 + mf * 16 + quad * 4 + r;
        int col = cc0 + (w >> 1) * 64 + nf * 16 + l16;
        out[(size_t)row * 1024 + col] = f2bf(acc[mf][nf][r]);
      }
}

// ---------------------------------------------------------------------------
// tree_fused: ONE block per (b, d) chain — grid (128, 2), **512 thr** (8
// waves: mh = w&1 m-half, jw = w>>1 j-quarter), 1 blk/CU. Chains are fully
// independent -> no grid sync / fences; __syncthreads() suffices (block
// reads only its own global writes).
// Per level, M-tiles of 32 nodes: gather A rows into LDS bf16, MFMA against
// fragment-swizzled W_h read from L2 (contiguous 1KB/B-fragment), fused
// gating epilogue. xp reads are NON-TEMPORAL so the once-streamed 134MB xp
// doesn't evict the 1MB W_h from L2.
// ---------------------------------------------------------------------------
__global__ __launch_bounds__(512, 1) void tree_fused(
    const int* __restrict__ lev_g, const int* __restrict__ csr_off_g,
    const int* __restrict__ csr_dat_g, const int* __restrict__ parents,
    const unsigned short* __restrict__ w16hf, const float* __restrict__ bias,
    const unsigned short* __restrict__ xp,
    float* __restrict__ cells, float* __restrict__ hidd) {
  __shared__ unsigned short As[32 * 264];
  __shared__ int lvl[256], ord[256], parL[256], cdat[256];
  __shared__ int coff[257];
  __shared__ int hist[NLEV], loff[NLEV + 1], cur[NLEV];

  int b = blockIdx.x, d = blockIdx.y, t = threadIdx.x;
  int w = t >> 6, lane = t & 63, l16 = lane & 15, quad = lane >> 4;
  int mh = w & 1, jw = w >> 1;
  int gr = t >> 4, gs = t & 15;   // gather: row 0..31, 16-float segment 0..15

  if (t < 256) {
    lvl[t]  = lev_g[d * 32768 + b * 256 + t];
    parL[t] = parents[t * BB + b];
    cdat[t] = csr_dat_g[b * 256 + t];
  }
  if (t < 257) coff[t] = csr_off_g[b * 260 + t];
  if (t < NLEV) hist[t] = 0;
  __syncthreads();
  if (t < 256) atomicAdd(&hist[lvl[t]], 1);
  __syncthreads();
  if (t == 0) {
    int s = 0;
    for (int l = 0; l < NLEV; ++l) { loff[l] = s; s += hist[l]; }
    loff[NLEV] = s;
  }
  __syncthreads();
  if (t < NLEV) cur[t] = loff[t];
  __syncthreads();
  if (t < 256) { int pos = atomicAdd(&cur[lvl[t]], 1); ord[pos] = t; }
  __syncthreads();

  const float* brow = bias + d * 1024;
  const unsigned short* Wf = w16hf + (size_t)d * 262144u;
  const unsigned short* xpd = xp + (size_t)d * 33554432u;

  for (int l = 0; l < NLEV; ++l) {
    int n0 = loff[l], np = loff[l + 1] - n0;
    if (np == 0) continue;
    int ntiles = (np + 31) >> 5;
    for (int mt = 0; mt < ntiles; ++mt) {
      // ---- gather A rows: sum children h (dt) / parent h (td) -> bf16 LDS
      {
        int i = mt * 32 + gr;
        if (i < np) {
          float av[16];
#pragma unroll
          for (int q = 0; q < 16; ++q) av[q] = 0.f;
          int node = ord[n0 + i];
          if (d == 0) {
            int o0 = coff[node], o1 = coff[node + 1];
            for (int e = o0; e < o1; ++e) {
              const float4* hb = (const float4*)(hidd +
                  ((size_t)cdat[e] * BB + b) * 512 + gs * 16);
#pragma unroll
              for (int q = 0; q < 4; ++q) {
                float4 v = hb[q];
                av[q*4+0] += v.x; av[q*4+1] += v.y; av[q*4+2] += v.z; av[q*4+3] += v.w;
              }
            }
          } else {
            int par = parL[node];
            if (par != LL) {
              const float4* hb = (const float4*)(hidd +
                  ((size_t)par * BB + b) * 512 + 256 + gs * 16);
#pragma unroll
              for (int q = 0; q < 4; ++q) {
                float4 v = hb[q];
                av[q*4+0] = v.x; av[q*4+1] = v.y; av[q*4+2] = v.z; av[q*4+3] = v.w;
              }
            }
          }
#pragma unroll
          for (int q = 0; q < 2; ++q) {
            short8 o;
#pragma unroll
            for (int e = 0; e < 8; ++e) o[e] = (short)f2bf(av[q * 8 + e]);
            *(short8*)&As[gr * 264 + gs * 16 + q * 8] = o;
          }
        }
      }
      __syncthreads();

      // ---- MFMA: A from LDS, B fragments from L2 (1KB coalesced each)
      short8 a[8];
#pragma unroll
      for (int ks = 0; ks < 8; ++ks)
        a[ks] = *(const short8*)&As[(mh * 16 + l16) * 264 + ks * 32 + quad * 8];
      floatx4 acc[4][4];
#pragma unroll
      for (int g = 0; g < 4; ++g)
#pragma unroll
        for (int jj = 0; jj < 4; ++jj) acc[g][jj] = (floatx4){0.f, 0.f, 0.f, 0.f};
#pragma unroll
      for (int ks = 0; ks < 8; ++ks)
#pragma unroll
        for (int g = 0; g < 4; ++g)
#pragma unroll
          for (int jj = 0; jj < 4; ++jj) {
            int nf = g * 16 + jw * 4 + jj;
            short8 bf = *(const short8*)(Wf + ((size_t)(nf * 8 + ks) * 64 + lane) * 8);
            acc[g][jj] = __builtin_amdgcn_mfma_f32_16x16x32_bf16(a[ks], bf, acc[g][jj], 0, 0, 0);
          }
      __syncthreads();

      // ---- epilogue: bias + xproj(non-temporal) + gating; sc lane-local
#pragma unroll
      for (int r = 0; r < 4; ++r) {
        int i = mt * 32 + mh * 16 + quad * 4 + r;
        if (i >= np) continue;
        int node = ord[n0 + i];
        float scv[4] = {0.f, 0.f, 0.f, 0.f};
        int jb = jw * 64 + l16;
        if (d == 0) {
          int o0 = coff[node], o1 = coff[node + 1];
          for (int e = o0; e < o1; ++e) {
            const float* cb = cells + ((size_t)cdat[e] * BB + b) * 512;
            scv[0] += cb[jb];      scv[1] += cb[jb + 16];
            scv[2] += cb[jb + 32]; scv[3] += cb[jb + 48];
          }
        } else {
          int par = parL[node];
          if (par != LL) {
            const float* cb = cells + ((size_t)par * BB + b) * 512 + 256;
            scv[0] = cb[jb];      scv[1] = cb[jb + 16];
            scv[2] = cb[jb + 32]; scv[3] = cb[jb + 48];
          }
        }
        const unsigned short* xr = xpd + ((size_t)node * BB + b) * 1024;
        size_t ob = ((size_t)node * BB + b) * 512 + (d << 8);
#pragma unroll
        for (int jj = 0; jj < 4; ++jj) {
          int j = jw * 64 + jj * 16 + l16;
          float pi = acc[0][jj][r] + brow[j]       + bf2f(__builtin_nontemporal_load(xr + j));
          float po = acc[1][jj][r] + brow[256 + j] + bf2f(__builtin_nontemporal_load(xr + 256 + j));
          float pu = acc[2][jj][r] + brow[512 + j] + bf2f(__builtin_nontemporal_load(xr + 512 + j));
          float pf = acc[3][jj][r] + brow[768 + j] + bf2f(__builtin_nontemporal_load(xr + 768 + j));
          float gi_ = sigm(pi), go = sigm(po), gu = tanh_(pu), gf = sigm(pf);
          float c = gi_ * gu + gf * scv[jj];
          float h = go * tanh_(c);
          cells[ob + j] = c;
          hidd[ob + j]  = h;
        }
      }
      __syncthreads();   // h/c stores drained before next level's gather
    }
  }
}

// ---------------------------------------------------------------------------
extern "C" void kernel_launch(void* const* d_in, const int* in_sizes, int n_in,
                              void* d_out, int out_size, void* d_ws, size_t ws_size,
                              hipStream_t stream) {
  Params p;
  p.inputs = (const float*)d_in[0];
  const int* parents = (const int*)d_in[2];
  for (int d = 0; d < 2; ++d) {
    int o = 3 + d * 8;
    p.ioux_w[d] = (const float*)d_in[o + 0];
    p.ioux_b[d] = (const float*)d_in[o + 1];
    p.iouh_w[d] = (const float*)d_in[o + 2];
    p.iouh_b[d] = (const float*)d_in[o + 3];
    p.fx_w[d]   = (const float*)d_in[o + 4];
    p.fx_b[d]   = (const float*)d_in[o + 5];
    p.fh_w[d]   = (const float*)d_in[o + 6];
    p.fh_b[d]   = (const float*)d_in[o + 7];
  }

  unsigned short* a16   = (unsigned short*)d_ws;        // 8,388,608 u16
  unsigned short* w16x  = a16 + 8388608u;               // 524,288
  unsigned short* w16h  = w16x + 524288u;               // 524,288 (fragment layout)
  unsigned short* xp    = w16h + 524288u;               // 67,108,864
  unsigned short* A16ws = xp + 67108864u;               // 16,777,216 (unused)
  float* bias = (float*)(A16ws + 16777216u);            // 2048 f32
  int*   lev_g   = (int*)(bias + 2048u);                // 65,536
  int*   csr_off = lev_g + 65536;                       // 33,280
  int*   csr_dat = csr_off + 33280;                     // 32,768
  int*   lvcnt   = csr_dat + 32768;                     // 96

  float* cells = (float*)d_out;                         // [256][128][512]
  float* hidd  = cells + 16777216u;

  prep_kernel<<<dim3(1024), dim3(256), 0, stream>>>(p, a16, w16x, w16h, bias, lvcnt);
  levels_kernel<<<dim3(128), dim3(256), 0, stream>>>(parents, lev_g, csr_off, csr_dat, lvcnt);
  xproj_gemm<<<dim3(256, 16), dim3(256), 0, stream>>>(a16, w16x, xp);
  tree_fused<<<dim3(128, 2), dim3(512), 0, stream>>>(lev_g, csr_off, csr_dat,
      parents, w16h, bias, xp, cells, hidd);
}

// Round 22
// 1350.662 us; speedup vs baseline: 2.3108x; 2.3108x over previous
//
#include <hip/hip_runtime.h>

#define LL 256
#define BB 128
#define NLEV 48

typedef float  floatx4 __attribute__((ext_vector_type(4)));
typedef short  short8  __attribute__((ext_vector_type(8)));

struct Params {
  const float* inputs;
  const float* ioux_w[2]; const float* ioux_b[2];
  const float* iouh_w[2]; const float* iouh_b[2];
  const float* fx_w[2];   const float* fx_b[2];
  const float* fh_w[2];   const float* fh_b[2];
};

__device__ __forceinline__ unsigned short f2bf(float f) {
  unsigned u = __float_as_uint(f);
  u += 0x7fffu + ((u >> 16) & 1u);
  return (unsigned short)(u >> 16);
}
__device__ __forceinline__ float bf2f(unsigned u) { return __uint_as_float(u << 16); }
__device__ __forceinline__ float sigm(float x) { return 1.0f / (1.0f + __expf(-x)); }
__device__ __forceinline__ float tanh_(float x) { return 1.0f - 2.0f / (1.0f + __expf(2.0f * x)); }

// ---------------------------------------------------------------------------
// prep: bf16 inputs; w16x row-major gate-planar (xproj GEMM); w16h in MFMA
// B-FRAGMENT layout: value(d, cc, k) at [((d*64+nf)*8+ks)*512 + lane*8 + e],
// nf=cc>>4, lane=((k&31)>>3)*16+(cc&15), ks=k>>5, e=k&7 — one wave's
// B-fragment for (nf,ks) is a contiguous, coalesced 1KB load.
// ---------------------------------------------------------------------------
__global__ __launch_bounds__(256) void prep_kernel(Params p,
    unsigned short* a16, unsigned short* w16x, unsigned short* w16h,
    float* bias, int* lvcnt) {
  size_t tid = (size_t)blockIdx.x * blockDim.x + threadIdx.x;
  size_t nth = (size_t)gridDim.x * blockDim.x;

  const float4* in4 = (const float4*)p.inputs;
  for (size_t i = tid; i < 2097152u; i += nth) {
    float4 v = in4[i];
    ((ushort4*)a16)[i] = make_ushort4(f2bf(v.x), f2bf(v.y), f2bf(v.z), f2bf(v.w));
  }
  for (size_t i = tid; i < 524288u; i += nth) {
    int d = (int)(i >> 18); int r = (int)(i & 262143);
    int cc = r >> 8; int k = r & 255;
    float sx = (cc < 768) ? p.ioux_w[d][cc * 256 + k] : p.fx_w[d][(cc - 768) * 256 + k];
    float sh = (cc < 768) ? p.iouh_w[d][cc * 256 + k] : p.fh_w[d][(cc - 768) * 256 + k];
    w16x[i] = f2bf(sx);
    int nf = cc >> 4, lcc = cc & 15;
    int ks = k >> 5, kr = k & 31;
    int lane = (kr >> 3) * 16 + lcc, e = kr & 7;
    w16h[((size_t)(d * 64 + nf) * 8 + ks) * 512 + lane * 8 + e] = f2bf(sh);
  }
  for (size_t i = tid; i < 2048u; i += nth) {
    int d = (int)(i >> 10); int cc = (int)(i & 1023);
    bias[i] = (cc < 768) ? (p.ioux_b[d][cc] + p.iouh_b[d][cc])
                         : (p.fx_b[d][cc - 768] + p.fh_b[d][cc - 768]);
  }
  for (size_t i = tid; i < 2u * NLEV; i += nth) lvcnt[i] = 0;
}

// ---------------------------------------------------------------------------
// levels: per-b tree walks -> dt heights, td depths; children CSR.
// ---------------------------------------------------------------------------
__global__ __launch_bounds__(256) void levels_kernel(
    const int* __restrict__ parents, int* __restrict__ lev_g,
    int* __restrict__ csr_off, int* __restrict__ csr_dat, int* __restrict__ lvcnt) {
  __shared__ int parL[256], lvdt[256], lvtd[256];
  __shared__ int cmax[257], ccnt[257], coff[257], ccur[257];
  int b = blockIdx.x, t = threadIdx.x;

  parL[t] = parents[t * BB + b];
  for (int v = t; v < 257; v += 256) { cmax[v] = -1; ccnt[v] = 0; }
  __syncthreads();

  if (t == 0) {
    lvtd[0] = 0;
    for (int i = 1; i < 256; ++i) lvtd[i] = lvtd[parL[i]] + 1;
  }
  if (t == 1) {
    for (int i = 255; i >= 1; --i) {
      int l = cmax[i] + 1;
      lvdt[i] = l;
      int p = parL[i];
      if (cmax[p] < l) cmax[p] = l;
    }
    lvdt[0] = cmax[0] + 1;
  }
  __syncthreads();

  int l1 = min(lvdt[t], NLEV - 1);
  int l2 = min(lvtd[t], NLEV - 1);
  if (t >= 1) atomicAdd(&ccnt[parL[t]], 1);
  lev_g[b * 256 + t] = l1;
  lev_g[32768 + b * 256 + t] = l2;
  __syncthreads();

  if (t == 0) {
    int s = 0;
    for (int i = 0; i < 257; ++i) { coff[i] = s; s += ccnt[i]; }
  }
  __syncthreads();
  for (int v = t; v < 257; v += 256) ccur[v] = coff[v];
  __syncthreads();
  if (t >= 1) {
    int pos = atomicAdd(&ccur[parL[t]], 1);
    csr_dat[b * 256 + pos] = t;
  }
  for (int v = t; v < 257; v += 256) csr_off[b * 260 + v] = coff[v];
}

// ---------------------------------------------------------------------------
// xproj GEMM, tiled: 128x128 tile, BK=64, LDS-staged. Grid (256, 16).
// ---------------------------------------------------------------------------
__global__ __launch_bounds__(256) void xproj_gemm(
    const unsigned short* __restrict__ a16,
    const unsigned short* __restrict__ w16x,
    unsigned short* __restrict__ xp) {
  __shared__ unsigned short As[128 * 72], Bs[128 * 72];
  int t = threadIdx.x;
  int w = t >> 6, lane = t & 63, l16 = lane & 15, quad = lane >> 4;
  int m0 = blockIdx.x * 128;
  int d = blockIdx.y >> 3;
  int cc0 = (blockIdx.y & 7) * 128;
  const unsigned short* Bg = w16x + ((size_t)d * 1024 + cc0) * 256;
  int lr = t >> 3, seg = t & 7;

  floatx4 acc[4][4];
#pragma unroll
  for (int i = 0; i < 4; ++i)
#pragma unroll
    for (int j = 0; j < 4; ++j) acc[i][j] = (floatx4){0.f, 0.f, 0.f, 0.f};

  for (int ck = 0; ck < 4; ++ck) {
    int k0 = ck * 64;
#pragma unroll
    for (int it = 0; it < 4; ++it) {
      int row = it * 32 + lr;
      *(uint4*)&As[row * 72 + seg * 8] =
          *(const uint4*)(a16 + (size_t)(m0 + row) * 256 + k0 + seg * 8);
      *(uint4*)&Bs[row * 72 + seg * 8] =
          *(const uint4*)(Bg + (size_t)row * 256 + k0 + seg * 8);
    }
    __syncthreads();
#pragma unroll
    for (int kc = 0; kc < 2; ++kc) {
      int kg = kc * 4 + quad;
      short8 af[4], bf[4];
#pragma unroll
      for (int mf = 0; mf < 4; ++mf)
        af[mf] = *(const short8*)&As[((w & 1) * 64 + mf * 16 + l16) * 72 + kg * 8];
#pragma unroll
      for (int nf = 0; nf < 4; ++nf)
        bf[nf] = *(const short8*)&Bs[((w >> 1) * 64 + nf * 16 + l16) * 72 + kg * 8];
#pragma unroll
      for (int mf = 0; mf < 4; ++mf)
#pragma unroll
        for (int nf = 0; nf < 4; ++nf)
          acc[mf][nf] = __builtin_amdgcn_mfma_f32_16x16x32_bf16(af[mf], bf[nf], acc[mf][nf], 0, 0, 0);
    }
    __syncthreads();
  }
  unsigned short* out = xp + (size_t)d * 33554432u;
#pragma unroll
  for (int mf = 0; mf < 4; ++mf)
#pragma unroll
    for (int nf = 0; nf < 4; ++nf)
#pragma unroll
      for (int r = 0; r < 4; ++r) {
        int row = m0 + (w & 1) * 64 + mf * 16 + quad * 4 + r;
        int col = cc0 + (w >> 1) * 64 + nf * 16 + l16;
        out[(size_t)row * 1024 + col] = f2bf(acc[mf][nf][r]);
      }
}

// ---------------------------------------------------------------------------
// tree_fused: ONE block per (b, d) chain — 1-D grid of 256, 512 thr (8
// waves). Wave jw (=w) owns j-columns [jw*32, jw*32+32): nf = g*16 + jw*2
// + jj (jj 0..1), both 16-row m-halves in-wave -> NO duplicate W loads
// (512 KB per tile total, same as 4-wave version, 2x the latency hiding).
// acc[2][4][2]=64 VGPR + a[2][8]=64 -> ~160 VGPR, no spill at 2 waves/SIMD.
// XCD swizzle: xcd = id&7 chooses d = xcd&1 so each XCD's 32 blocks share
// ONE direction -> W footprint per XCD L2 = 512 KB.
// Chains are independent -> only __syncthreads() needed.
// ---------------------------------------------------------------------------
__global__ __launch_bounds__(512, 1) void tree_fused(
    const int* __restrict__ lev_g, const int* __restrict__ csr_off_g,
    const int* __restrict__ csr_dat_g, const int* __restrict__ parents,
    const unsigned short* __restrict__ w16hf, const float* __restrict__ bias,
    const unsigned short* __restrict__ xp,
    float* __restrict__ cells, float* __restrict__ hidd) {
  __shared__ unsigned short As[32 * 264];
  __shared__ int lvl[256], ord[256], parL[256], cdat[256];
  __shared__ int coff[257];
  __shared__ int hist[NLEV], loff[NLEV + 1], cur[NLEV];

  int id = blockIdx.x;
  int xcd = id & 7, kk = id >> 3;
  int d = xcd & 1;
  int b = (xcd >> 1) * 32 + kk;
  int t = threadIdx.x;
  int jw = t >> 6, lane = t & 63, l16 = lane & 15, quad = lane >> 4;
  int gr = t >> 4, gs = t & 15;   // gather: row 0..31, 16-float segment

  if (t < 256) {
    lvl[t]  = lev_g[d * 32768 + b * 256 + t];
    parL[t] = parents[t * BB + b];
    cdat[t] = csr_dat_g[b * 256 + t];
  }
  if (t < 257) coff[t] = csr_off_g[b * 260 + t];
  if (t < NLEV) hist[t] = 0;
  __syncthreads();
  if (t < 256) atomicAdd(&hist[lvl[t]], 1);
  __syncthreads();
  if (t == 0) {
    int s = 0;
    for (int l = 0; l < NLEV; ++l) { loff[l] = s; s += hist[l]; }
    loff[NLEV] = s;
  }
  __syncthreads();
  if (t < NLEV) cur[t] = loff[t];
  __syncthreads();
  if (t < 256) { int pos = atomicAdd(&cur[lvl[t]], 1); ord[pos] = t; }
  __syncthreads();

  const float* brow = bias + d * 1024;
  const unsigned short* Wf = w16hf + (size_t)d * 262144u;
  const unsigned short* xpd = xp + (size_t)d * 33554432u;

  for (int l = 0; l < NLEV; ++l) {
    int n0 = loff[l], np = loff[l + 1] - n0;
    if (np == 0) continue;
    int ntiles = (np + 31) >> 5;
    for (int mt = 0; mt < ntiles; ++mt) {
      // ---- gather A rows: sum children h (dt) / parent h (td) -> bf16 LDS
      {
        int i = mt * 32 + gr;
        if (i < np) {
          float av[16];
#pragma unroll
          for (int q = 0; q < 16; ++q) av[q] = 0.f;
          int node = ord[n0 + i];
          if (d == 0) {
            int o0 = coff[node], o1 = coff[node + 1];
            for (int e = o0; e < o1; ++e) {
              const float4* hb = (const float4*)(hidd +
                  ((size_t)cdat[e] * BB + b) * 512 + gs * 16);
#pragma unroll
              for (int q = 0; q < 4; ++q) {
                float4 v = hb[q];
                av[q*4+0] += v.x; av[q*4+1] += v.y; av[q*4+2] += v.z; av[q*4+3] += v.w;
              }
            }
          } else {
            int par = parL[node];
            if (par != LL) {
              const float4* hb = (const float4*)(hidd +
                  ((size_t)par * BB + b) * 512 + 256 + gs * 16);
#pragma unroll
              for (int q = 0; q < 4; ++q) {
                float4 v = hb[q];
                av[q*4+0] = v.x; av[q*4+1] = v.y; av[q*4+2] = v.z; av[q*4+3] = v.w;
              }
            }
          }
#pragma unroll
          for (int q = 0; q < 2; ++q) {
            short8 o;
#pragma unroll
            for (int e = 0; e < 8; ++e) o[e] = (short)f2bf(av[q * 8 + e]);
            *(short8*)&As[gr * 264 + gs * 16 + q * 8] = o;
          }
        }
      }
      __syncthreads();

      // ---- MFMA: A (both 16-row halves) from LDS, B fragments from L2;
      //      each bf load feeds 2 MFMAs (mh=0,1) -> no duplicate W traffic.
      short8 a[2][8];
#pragma unroll
      for (int mh = 0; mh < 2; ++mh)
#pragma unroll
        for (int ks = 0; ks < 8; ++ks)
          a[mh][ks] = *(const short8*)&As[(mh * 16 + l16) * 264 + ks * 32 + quad * 8];
      floatx4 acc[2][4][2];
#pragma unroll
      for (int mh = 0; mh < 2; ++mh)
#pragma unroll
        for (int g = 0; g < 4; ++g)
#pragma unroll
          for (int jj = 0; jj < 2; ++jj) acc[mh][g][jj] = (floatx4){0.f, 0.f, 0.f, 0.f};
#pragma unroll
      for (int ks = 0; ks < 8; ++ks)
#pragma unroll
        for (int g = 0; g < 4; ++g)
#pragma unroll
          for (int jj = 0; jj < 2; ++jj) {
            int nf = g * 16 + jw * 2 + jj;
            short8 bf = *(const short8*)(Wf + ((size_t)(nf * 8 + ks) * 64 + lane) * 8);
            acc[0][g][jj] = __builtin_amdgcn_mfma_f32_16x16x32_bf16(a[0][ks], bf, acc[0][g][jj], 0, 0, 0);
            acc[1][g][jj] = __builtin_amdgcn_mfma_f32_16x16x32_bf16(a[1][ks], bf, acc[1][g][jj], 0, 0, 0);
          }
      __syncthreads();

      // ---- epilogue: bias + xproj(non-temporal) + gating; wave's j-window
      //      is [jw*32, jw*32+32)
#pragma unroll
      for (int mh = 0; mh < 2; ++mh)
#pragma unroll
        for (int r = 0; r < 4; ++r) {
          int i = mt * 32 + mh * 16 + quad * 4 + r;
          if (i >= np) continue;
          int node = ord[n0 + i];
          float scv[2] = {0.f, 0.f};
          int jb = jw * 32 + l16;
          if (d == 0) {
            int o0 = coff[node], o1 = coff[node + 1];
            for (int e = o0; e < o1; ++e) {
              const float* cb = cells + ((size_t)cdat[e] * BB + b) * 512;
              scv[0] += cb[jb];
              scv[1] += cb[jb + 16];
            }
          } else {
            int par = parL[node];
            if (par != LL) {
              const float* cb = cells + ((size_t)par * BB + b) * 512 + 256;
              scv[0] = cb[jb];
              scv[1] = cb[jb + 16];
            }
          }
          const unsigned short* xr = xpd + ((size_t)node * BB + b) * 1024;
          size_t ob = ((size_t)node * BB + b) * 512 + (d << 8);
#pragma unroll
          for (int jj = 0; jj < 2; ++jj) {
            int j = jw * 32 + jj * 16 + l16;
            float pi = acc[mh][0][jj][r] + brow[j]       + bf2f(__builtin_nontemporal_load(xr + j));
            float po = acc[mh][1][jj][r] + brow[256 + j] + bf2f(__builtin_nontemporal_load(xr + 256 + j));
            float pu = acc[mh][2][jj][r] + brow[512 + j] + bf2f(__builtin_nontemporal_load(xr + 512 + j));
            float pf = acc[mh][3][jj][r] + brow[768 + j] + bf2f(__builtin_nontemporal_load(xr + 768 + j));
            float gi_ = sigm(pi), go = sigm(po), gu = tanh_(pu), gf = sigm(pf);
            float c = gi_ * gu + gf * scv[jj];
            float h = go * tanh_(c);
            cells[ob + j] = c;
            hidd[ob + j]  = h;
          }
        }
      __syncthreads();   // h/c stores drained before next level's gather
    }
  }
}

// ---------------------------------------------------------------------------
extern "C" void kernel_launch(void* const* d_in, const int* in_sizes, int n_in,
                              void* d_out, int out_size, void* d_ws, size_t ws_size,
                              hipStream_t stream) {
  Params p;
  p.inputs = (const float*)d_in[0];
  const int* parents = (const int*)d_in[2];
  for (int d = 0; d < 2; ++d) {
    int o = 3 + d * 8;
    p.ioux_w[d] = (const float*)d_in[o + 0];
    p.ioux_b[d] = (const float*)d_in[o + 1];
    p.iouh_w[d] = (const float*)d_in[o + 2];
    p.iouh_b[d] = (const float*)d_in[o + 3];
    p.fx_w[d]   = (const float*)d_in[o + 4];
    p.fx_b[d]   = (const float*)d_in[o + 5];
    p.fh_w[d]   = (const float*)d_in[o + 6];
    p.fh_b[d]   = (const float*)d_in[o + 7];
  }

  unsigned short* a16   = (unsigned short*)d_ws;        // 8,388,608 u16
  unsigned short* w16x  = a16 + 8388608u;               // 524,288
  unsigned short* w16h  = w16x + 524288u;               // 524,288 (fragment layout)
  unsigned short* xp    = w16h + 524288u;               // 67,108,864
  unsigned short* A16ws = xp + 67108864u;               // 16,777,216 (unused)
  float* bias = (float*)(A16ws + 16777216u);            // 2048 f32
  int*   lev_g   = (int*)(bias + 2048u);                // 65,536
  int*   csr_off = lev_g + 65536;                       // 33,280
  int*   csr_dat = csr_off + 33280;                     // 32,768
  int*   lvcnt   = csr_dat + 32768;                     // 96

  float* cells = (float*)d_out;                         // [256][128][512]
  float* hidd  = cells + 16777216u;

  prep_kernel<<<dim3(1024), dim3(256), 0, stream>>>(p, a16, w16x, w16h, bias, lvcnt);
  levels_kernel<<<dim3(128), dim3(256), 0, stream>>>(parents, lev_g, csr_off, csr_dat, lvcnt);
  xproj_gemm<<<dim3(256, 16), dim3(256), 0, stream>>>(a16, w16x, xp);
  tree_fused<<<dim3(256), dim3(512), 0, stream>>>(lev_g, csr_off, csr_dat,
      parents, w16h, bias, xp, cells, hidd);
}